// Round 8
// baseline (187.330 us; speedup 1.0000x reference)
//
#include <hip/hip_runtime.h>

// ---------------------------------------------------------------------------
// GraphConv (DGL norm='both') + residual linear:
//   out = (D_dst^-1/2 * A^T * (D_src^-1/2 * x)) @ W + x @ Wr + (b + br)
// Round 8: 64B-padded histogram counters (defeat cache-line serialization at
// the TCC atomic units), rank capture -> atomic-free scatter, float4 gather,
// VGPR-weight epilogue.
// ---------------------------------------------------------------------------

#define P 16   // counter padding stride in ints (64 B)

// 1 edge per thread, padded counters: 2 atomics, lines ~2 counters each.
__global__ void hist_kernel(const int* __restrict__ src, const int* __restrict__ dst,
                            int* __restrict__ cs, int* __restrict__ cd,
                            unsigned short* __restrict__ rank, int e) {
    int i = blockIdx.x * blockDim.x + threadIdx.x;
    if (i < e) {
        atomicAdd(&cs[src[i] * P], 1);
        rank[i] = (unsigned short)atomicAdd(&cd[dst[i] * P], 1);
    }
}

// ns[i] = rsqrt(max(out_deg,1))
__global__ void norm_src_kernel(const int* __restrict__ cs, float* __restrict__ ns, int n) {
    int i = blockIdx.x * blockDim.x + threadIdx.x;
    if (i < n) ns[i] = rsqrtf((float)max(cs[i * P], 1));
}

// Scan phase A over n padded counts: 4096 counters/block (256 thr x 16).
__global__ void partial_kernel(const int* __restrict__ cnt, int* __restrict__ part, int m) {
    __shared__ int sm[256];
    int t = threadIdx.x;
    int base = blockIdx.x * 4096 + t * 16;
    int s = 0;
    for (int k = 0; k < 16; ++k)
        if (base + k < m) s += cnt[(base + k) * P];
    sm[t] = s;
    __syncthreads();
    for (int st = 128; st > 0; st >>= 1) {
        if (t < st) sm[t] += sm[t + st];
        __syncthreads();
    }
    if (t == 0) part[blockIdx.x] = sm[0];
}

// Scan phase B: single-block exclusive scan of the partials (nb <= 256).
__global__ void scan_part_kernel(int* __restrict__ part, int nb) {
    __shared__ int sm[256];
    int t = threadIdx.x;
    int v = (t < nb) ? part[t] : 0;
    sm[t] = v;
    __syncthreads();
    for (int d = 1; d < 256; d <<= 1) {
        int add = (t >= d) ? sm[t - d] : 0;
        __syncthreads();
        sm[t] += add;
        __syncthreads();
    }
    if (t < nb) part[t] = sm[t] - v;   // exclusive
}

// Scan phase C: exclusive scan of padded cd -> dense roff (n+1, roff[n]=e).
__global__ void scan_final_kernel(const int* __restrict__ cnt, const int* __restrict__ part,
                                  int* __restrict__ roff, int m, int e) {
    __shared__ int sm[256];
    int t = threadIdx.x;
    int base = blockIdx.x * 4096 + t * 16;
    int v[16];
    #pragma unroll
    for (int k = 0; k < 16; ++k) v[k] = (base + k < m) ? cnt[(base + k) * P] : 0;
    int s = 0;
    #pragma unroll
    for (int k = 0; k < 16; ++k) { int x = v[k]; v[k] = s; s += x; }
    sm[t] = s;
    __syncthreads();
    for (int d = 1; d < 256; d <<= 1) {
        int add = (t >= d) ? sm[t - d] : 0;
        __syncthreads();
        sm[t] += add;
        __syncthreads();
    }
    int tb = sm[t] - s + part[blockIdx.x];
    #pragma unroll
    for (int k = 0; k < 16; ++k)
        if (base + k < m) roff[base + k] = v[k] + tb;
    if (base == 0 && t == 0) roff[m] = e;
}

// Atomic-free scatter: slot = roff[dst] + rank. 1 edge/thread for TLP.
__global__ void scatter_kernel(const int* __restrict__ src, const int* __restrict__ dst,
                               const int* __restrict__ roff,
                               const unsigned short* __restrict__ rank,
                               int* __restrict__ col, int e) {
    int i = blockIdx.x * blockDim.x + threadIdx.x;
    if (i < e) col[roff[dst[i]] + rank[i]] = src[i];
}

// xs = x * ns[node], float4-vectorized.
__global__ void prescale_kernel(const float4* __restrict__ x4, const float* __restrict__ ns,
                                float4* __restrict__ xs4, int n16) {
    int i = blockIdx.x * blockDim.x + threadIdx.x;
    if (i < n16) {
        float s = ns[i >> 4];
        float4 v = x4[i];
        v.x *= s; v.y *= s; v.z *= s; v.w *= s;
        xs4[i] = v;
    }
}

// One wave per node. Lane = (edge-slot g = lane>>4) x (feature-quad q = lane&15).
// agg[node] = rsqrt(max(in_deg,1)) * sum_{s in N(node)} xs[s]; in_deg = end-beg.
__global__ __launch_bounds__(256) void gather_kernel(
    const float4* __restrict__ xs4, const int* __restrict__ col,
    const int* __restrict__ roff,
    float4* __restrict__ agg4, int n) {
    int lane = threadIdx.x & 63;
    int node = (blockIdx.x * 256 + threadIdx.x) >> 6;
    if (node >= n) return;
    node = __builtin_amdgcn_readfirstlane(node);   // wave-uniform -> scalar loads

    int beg = roff[node];
    int end = roff[node + 1];
    int g = lane >> 4;   // edge sub-slot 0..3
    int q = lane & 15;   // feature quad 0..15

    float4 acc = make_float4(0.f, 0.f, 0.f, 0.f);
    int j = beg;
    for (; j + 8 <= end; j += 8) {          // 8 edges: two 16B loads in flight
        int s0 = col[j + g];
        int s1 = col[j + 4 + g];
        float4 v0 = xs4[(long)s0 * 16 + q];
        float4 v1 = xs4[(long)s1 * 16 + q];
        acc.x += v0.x + v1.x;
        acc.y += v0.y + v1.y;
        acc.z += v0.z + v1.z;
        acc.w += v0.w + v1.w;
    }
    for (; j < end; j += 4) {               // predicated 4-edge tail
        int jj = j + g;
        int s   = (jj < end) ? col[jj] : node;   // safe dummy index
        float m = (jj < end) ? 1.f : 0.f;
        float4 v = xs4[(long)s * 16 + q];
        acc.x += v.x * m;
        acc.y += v.y * m;
        acc.z += v.z * m;
        acc.w += v.w * m;
    }

    // reduce across the 4 edge-slots (lanes q, q+16, q+32, q+48)
    acc.x += __shfl_down(acc.x, 32);
    acc.y += __shfl_down(acc.y, 32);
    acc.z += __shfl_down(acc.z, 32);
    acc.w += __shfl_down(acc.w, 32);
    acc.x += __shfl_down(acc.x, 16);
    acc.y += __shfl_down(acc.y, 16);
    acc.z += __shfl_down(acc.z, 16);
    acc.w += __shfl_down(acc.w, 16);

    float nd = rsqrtf((float)max(end - beg, 1));
    if (lane < 16) {
        acc.x *= nd; acc.y *= nd; acc.z *= nd; acc.w *= nd;
        agg4[(long)node * 16 + q] = acc;
    }
}

// out[r][c] = agg[r][:]@W[:,c] + x[r][:]@Wr[:,c] + (b+br)[c]
// Lane c holds W[:,c], Wr[:,c] in VGPRs (static unroll); rows staged in LDS.
#define OR 32
__global__ __launch_bounds__(256) void out_kernel(
    const float4* __restrict__ agg4, const float4* __restrict__ x4,
    const float* __restrict__ W, const float* __restrict__ b,
    const float* __restrict__ Wr, const float* __restrict__ br,
    float* __restrict__ out, int n) {
    __shared__ float4 sA[OR * 16];
    __shared__ float4 sX[OR * 16];
    int t = threadIdx.x;
    int c = t & 63;
    int base = blockIdx.x * OR;

    float4 wA[16], wR[16];
    #pragma unroll
    for (int q = 0; q < 16; ++q) {
        wA[q].x = W[(4 * q + 0) * 64 + c];
        wA[q].y = W[(4 * q + 1) * 64 + c];
        wA[q].z = W[(4 * q + 2) * 64 + c];
        wA[q].w = W[(4 * q + 3) * 64 + c];
        wR[q].x = Wr[(4 * q + 0) * 64 + c];
        wR[q].y = Wr[(4 * q + 1) * 64 + c];
        wR[q].z = Wr[(4 * q + 2) * 64 + c];
        wR[q].w = Wr[(4 * q + 3) * 64 + c];
    }

    #pragma unroll
    for (int i = 0; i < 2; ++i) {          // stage 32 rows of A and X
        int qi = t + 256 * i;              // 0..511
        int row = base + (qi >> 4);
        float4 z = make_float4(0.f, 0.f, 0.f, 0.f);
        sA[qi] = (row < n) ? agg4[(long)row * 16 + (qi & 15)] : z;
        sX[qi] = (row < n) ? x4[(long)row * 16 + (qi & 15)] : z;
    }
    __syncthreads();

    int w = t >> 6;
    float bias = b[c] + br[c];
    for (int r = w * 8; r < w * 8 + 8; ++r) {
        float a0 = 0.f, a1 = 0.f, r0 = 0.f, r1 = 0.f;
        #pragma unroll
        for (int q = 0; q < 16; q += 2) {
            float4 av0 = sA[r * 16 + q];
            float4 av1 = sA[r * 16 + q + 1];
            float4 xv0 = sX[r * 16 + q];
            float4 xv1 = sX[r * 16 + q + 1];
            a0 += av0.x * wA[q].x + av0.y * wA[q].y + av0.z * wA[q].z + av0.w * wA[q].w;
            a1 += av1.x * wA[q + 1].x + av1.y * wA[q + 1].y + av1.z * wA[q + 1].z + av1.w * wA[q + 1].w;
            r0 += xv0.x * wR[q].x + xv0.y * wR[q].y + xv0.z * wR[q].z + xv0.w * wR[q].w;
            r1 += xv1.x * wR[q + 1].x + xv1.y * wR[q + 1].y + xv1.z * wR[q + 1].z + xv1.w * wR[q + 1].w;
        }
        int grow = base + r;
        if (grow < n) out[(long)grow * 64 + c] = (a0 + a1) + (r0 + r1) + bias;
    }
}

extern "C" void kernel_launch(void* const* d_in, const int* in_sizes, int n_in,
                              void* d_out, int out_size, void* d_ws, size_t ws_size,
                              hipStream_t stream) {
    const float* x   = (const float*)d_in[0];
    const int*   src = (const int*)d_in[1];
    const int*   dst = (const int*)d_in[2];
    const float* W   = (const float*)d_in[3];
    const float* b   = (const float*)d_in[4];
    const float* Wr  = (const float*)d_in[5];
    const float* br  = (const float*)d_in[6];
    float* out = (float*)d_out;

    const int n = in_sizes[0] / 64;    // 50000
    const int e = in_sizes[1];         // 800000
    const int nbs = (n + 4095) / 4096; // 13 scan blocks

    int*   cs   = (int*)d_ws;              // n*P (padded counters)
    int*   cd   = cs + (size_t)n * P;      // n*P
    int*   roff = cd + (size_t)n * P;      // n+1
    int*   part = roff + n + 1;            // 256
    int*   col  = part + 256;              // e
    float* ns   = (float*)(col + e);       // n
    float* xs   = ns + n;                  // n*64
    float* agg  = xs + (size_t)n * 64;     // n*64
    unsigned short* rank = (unsigned short*)(agg + (size_t)n * 64); // e

    // zero the padded counters (12.8 MB, ~3 us)
    hipMemsetAsync(cs, 0, (size_t)2 * n * P * sizeof(int), stream);

    hist_kernel<<<(e + 255) / 256, 256, 0, stream>>>(src, dst, cs, cd, rank, e);

    norm_src_kernel<<<(n + 255) / 256, 256, 0, stream>>>(cs, ns, n);

    partial_kernel<<<nbs, 256, 0, stream>>>(cd, part, n);
    scan_part_kernel<<<1, 256, 0, stream>>>(part, nbs);
    scan_final_kernel<<<nbs, 256, 0, stream>>>(cd, part, roff, n, e);

    scatter_kernel<<<(e + 255) / 256, 256, 0, stream>>>(src, dst, roff, rank, col, e);

    prescale_kernel<<<(n * 16 + 255) / 256, 256, 0, stream>>>(
        (const float4*)x, ns, (float4*)xs, n * 16);

    gather_kernel<<<(n * 64 + 255) / 256, 256, 0, stream>>>(
        (const float4*)xs, col, roff, (float4*)agg, n);

    out_kernel<<<(n + OR - 1) / OR, 256, 0, stream>>>(
        (const float4*)agg, (const float4*)x, W, b, Wr, br, out, n);
}

// Round 9
// 136.707 us; speedup vs baseline: 1.3703x; 1.3703x over previous
//
#include <hip/hip_runtime.h>

// ---------------------------------------------------------------------------
// GraphConv (DGL norm='both') + residual linear:
//   out = (D_dst^-1/2 * A^T * (D_src^-1/2 * x)) @ W + x @ Wr + (b + br)
// Round 9: fully atomic-free CSR build (range bucketing + LDS histograms);
// global atomics eliminated (19 G transactions/s write-through wall).
// ---------------------------------------------------------------------------

#define TILE 4096   // edges per bucket block

// Per-block LDS histograms of dst>>8 and src>>8.
// H layout: H[bin*nb + blk] (dst), H[256*nb + bin*nb + blk] (src).
__global__ __launch_bounds__(256) void bucket_hist_kernel(
    const int* __restrict__ src, const int* __restrict__ dst,
    int* __restrict__ H, int e, int nb) {
    __shared__ int hd[256], hs[256];
    int t = threadIdx.x, blk = blockIdx.x;
    hd[t] = 0; hs[t] = 0;
    __syncthreads();
    int base = blk * TILE;
    #pragma unroll
    for (int s = 0; s < 16; ++s) {
        int j = base + s * 256 + t;
        if (j < e) {
            atomicAdd(&hd[dst[j] >> 8], 1);
            atomicAdd(&hs[src[j] >> 8], 1);
        }
    }
    __syncthreads();
    H[t * nb + blk]            = hd[t];
    H[256 * nb + t * nb + blk] = hs[t];
}

// Scan phase A: 4096 elems/block partial sums.
__global__ void partial_kernel(const int* __restrict__ cnt, int* __restrict__ part, int m) {
    __shared__ int sm[256];
    int t = threadIdx.x;
    int base = blockIdx.x * 4096 + t * 16;
    int s = 0;
    if (base + 16 <= m) {
        const int4* p = (const int4*)(cnt + base);
        #pragma unroll
        for (int k = 0; k < 4; ++k) { int4 v = p[k]; s += v.x + v.y + v.z + v.w; }
    } else {
        for (int k = 0; k < 16; ++k) if (base + k < m) s += cnt[base + k];
    }
    sm[t] = s;
    __syncthreads();
    for (int st = 128; st > 0; st >>= 1) {
        if (t < st) sm[t] += sm[t + st];
        __syncthreads();
    }
    if (t == 0) part[blockIdx.x] = sm[0];
}

// Scan phase B: single-block exclusive scan of partials (nb <= 256).
__global__ void scan_part_kernel(int* __restrict__ part, int nb) {
    __shared__ int sm[256];
    int t = threadIdx.x;
    int v = (t < nb) ? part[t] : 0;
    sm[t] = v;
    __syncthreads();
    for (int d = 1; d < 256; d <<= 1) {
        int add = (t >= d) ? sm[t - d] : 0;
        __syncthreads();
        sm[t] += add;
        __syncthreads();
    }
    if (t < nb) part[t] = sm[t] - v;   // exclusive
}

// Scan phase C: exclusive scan -> Hoff[0..m).
__global__ void scan_final_kernel(const int* __restrict__ cnt, const int* __restrict__ part,
                                  int* __restrict__ Hoff, int m) {
    __shared__ int sm[256];
    int t = threadIdx.x;
    int base = blockIdx.x * 4096 + t * 16;
    int v[16];
    #pragma unroll
    for (int k = 0; k < 16; ++k) v[k] = (base + k < m) ? cnt[base + k] : 0;
    int s = 0;
    #pragma unroll
    for (int k = 0; k < 16; ++k) { int x = v[k]; v[k] = s; s += x; }
    sm[t] = s;
    __syncthreads();
    for (int d = 1; d < 256; d <<= 1) {
        int add = (t >= d) ? sm[t - d] : 0;
        __syncthreads();
        sm[t] += add;
        __syncthreads();
    }
    int tb = sm[t] - s + part[blockIdx.x];
    #pragma unroll
    for (int k = 0; k < 16; ++k)
        if (base + k < m) Hoff[base + k] = v[k] + tb;
}

// Scatter edges into range buckets (plain cached stores; LDS cursors only).
__global__ __launch_bounds__(256) void bucket_scatter_kernel(
    const int* __restrict__ src, const int* __restrict__ dst,
    const int* __restrict__ Hoff,
    int* __restrict__ kdst, int* __restrict__ ksrc, int* __restrict__ ksrc2,
    int e, int nb) {
    __shared__ int dcur[256], scur[256];
    int t = threadIdx.x, blk = blockIdx.x;
    dcur[t] = Hoff[t * nb + blk];
    scur[t] = Hoff[256 * nb + t * nb + blk] - e;   // src offsets live in [e,2e)
    __syncthreads();
    int base = blk * TILE;
    #pragma unroll
    for (int s = 0; s < 16; ++s) {
        int j = base + s * 256 + t;
        if (j < e) {
            int d = dst[j], sv = src[j];
            int pd = atomicAdd(&dcur[d >> 8], 1);
            kdst[pd] = d;
            ksrc[pd] = sv;
            int ps = atomicAdd(&scur[sv >> 8], 1);
            ksrc2[ps] = sv;
        }
    }
}

// One block per 256-node range: LDS hist -> LDS scan -> roff + col.
__global__ __launch_bounds__(256) void csr_kernel(
    const int* __restrict__ kdst, const int* __restrict__ ksrc,
    const int* __restrict__ Hoff,
    int* __restrict__ roff, int* __restrict__ col,
    int n, int e, int nb, int nrange) {
    __shared__ int lh[256], sm[256];
    int t = threadIdx.x, r = blockIdx.x;
    int beg = Hoff[r * nb];
    int end = (r + 1 < nrange) ? Hoff[(r + 1) * nb] : e;
    lh[t] = 0;
    __syncthreads();
    for (int j = beg + t; j < end; j += 256)
        atomicAdd(&lh[kdst[j] & 255], 1);
    __syncthreads();
    int v0 = lh[t];
    sm[t] = v0;
    __syncthreads();
    for (int d = 1; d < 256; d <<= 1) {
        int add = (t >= d) ? sm[t - d] : 0;
        __syncthreads();
        sm[t] += add;
        __syncthreads();
    }
    int excl = sm[t] - v0;
    int v = r * 256 + t;
    if (v < n) roff[v] = beg + excl;
    __syncthreads();          // all v0 reads done before lh reuse
    lh[t] = excl;             // lh becomes the local cursor array
    __syncthreads();
    for (int j = beg + t; j < end; j += 256) {
        int d = kdst[j];
        int pos = beg + atomicAdd(&lh[d & 255], 1);
        col[pos] = ksrc[j];
    }
    if (r == 0 && t == 0) roff[n] = e;
}

// Out-degree norm from bucketed src: ns[v] = rsqrt(max(cnt,1)).
__global__ __launch_bounds__(256) void outdeg_kernel(
    const int* __restrict__ ksrc2, const int* __restrict__ Hoff,
    float* __restrict__ ns, int n, int e, int nb, int nrange) {
    __shared__ int lh[256];
    int t = threadIdx.x, r = blockIdx.x;
    int beg = Hoff[256 * nb + r * nb] - e;
    int end = (r + 1 < nrange) ? (Hoff[256 * nb + (r + 1) * nb] - e) : e;
    lh[t] = 0;
    __syncthreads();
    for (int j = beg + t; j < end; j += 256)
        atomicAdd(&lh[ksrc2[j] & 255], 1);
    __syncthreads();
    int v = r * 256 + t;
    if (v < n) ns[v] = rsqrtf((float)max(lh[t], 1));
}

// xs = x * ns[node], float4-vectorized.
__global__ void prescale_kernel(const float4* __restrict__ x4, const float* __restrict__ ns,
                                float4* __restrict__ xs4, int n16) {
    int i = blockIdx.x * blockDim.x + threadIdx.x;
    if (i < n16) {
        float s = ns[i >> 4];
        float4 v = x4[i];
        v.x *= s; v.y *= s; v.z *= s; v.w *= s;
        xs4[i] = v;
    }
}

// One wave per node. Lane = (edge-slot g = lane>>4) x (feature-quad q = lane&15).
__global__ __launch_bounds__(256) void gather_kernel(
    const float4* __restrict__ xs4, const int* __restrict__ col,
    const int* __restrict__ roff,
    float4* __restrict__ agg4, int n) {
    int lane = threadIdx.x & 63;
    int node = (blockIdx.x * 256 + threadIdx.x) >> 6;
    if (node >= n) return;
    node = __builtin_amdgcn_readfirstlane(node);   // wave-uniform -> scalar loads

    int beg = roff[node];
    int end = roff[node + 1];
    int g = lane >> 4;   // edge sub-slot 0..3
    int q = lane & 15;   // feature quad 0..15

    float4 acc = make_float4(0.f, 0.f, 0.f, 0.f);
    int j = beg;
    for (; j + 8 <= end; j += 8) {          // 8 edges: two 16B loads in flight
        int s0 = col[j + g];
        int s1 = col[j + 4 + g];
        float4 v0 = xs4[(long)s0 * 16 + q];
        float4 v1 = xs4[(long)s1 * 16 + q];
        acc.x += v0.x + v1.x;
        acc.y += v0.y + v1.y;
        acc.z += v0.z + v1.z;
        acc.w += v0.w + v1.w;
    }
    for (; j < end; j += 4) {               // predicated 4-edge tail
        int jj = j + g;
        int s   = (jj < end) ? col[jj] : node;   // safe dummy index
        float m = (jj < end) ? 1.f : 0.f;
        float4 v = xs4[(long)s * 16 + q];
        acc.x += v.x * m;
        acc.y += v.y * m;
        acc.z += v.z * m;
        acc.w += v.w * m;
    }

    acc.x += __shfl_down(acc.x, 32);
    acc.y += __shfl_down(acc.y, 32);
    acc.z += __shfl_down(acc.z, 32);
    acc.w += __shfl_down(acc.w, 32);
    acc.x += __shfl_down(acc.x, 16);
    acc.y += __shfl_down(acc.y, 16);
    acc.z += __shfl_down(acc.z, 16);
    acc.w += __shfl_down(acc.w, 16);

    float nd = rsqrtf((float)max(end - beg, 1));
    if (lane < 16) {
        acc.x *= nd; acc.y *= nd; acc.z *= nd; acc.w *= nd;
        agg4[(long)node * 16 + q] = acc;
    }
}

// out[r][c] = agg[r][:]@W[:,c] + x[r][:]@Wr[:,c] + (b+br)[c]
// Lane c holds W[:,c], Wr[:,c] in VGPRs (static unroll); rows staged in LDS.
#define OR 32
__global__ __launch_bounds__(256) void out_kernel(
    const float4* __restrict__ agg4, const float4* __restrict__ x4,
    const float* __restrict__ W, const float* __restrict__ b,
    const float* __restrict__ Wr, const float* __restrict__ br,
    float* __restrict__ out, int n) {
    __shared__ float4 sA[OR * 16];
    __shared__ float4 sX[OR * 16];
    int t = threadIdx.x;
    int c = t & 63;
    int base = blockIdx.x * OR;

    float4 wA[16], wR[16];
    #pragma unroll
    for (int q = 0; q < 16; ++q) {
        wA[q].x = W[(4 * q + 0) * 64 + c];
        wA[q].y = W[(4 * q + 1) * 64 + c];
        wA[q].z = W[(4 * q + 2) * 64 + c];
        wA[q].w = W[(4 * q + 3) * 64 + c];
        wR[q].x = Wr[(4 * q + 0) * 64 + c];
        wR[q].y = Wr[(4 * q + 1) * 64 + c];
        wR[q].z = Wr[(4 * q + 2) * 64 + c];
        wR[q].w = Wr[(4 * q + 3) * 64 + c];
    }

    #pragma unroll
    for (int i = 0; i < 2; ++i) {          // stage 32 rows of A and X
        int qi = t + 256 * i;              // 0..511
        int row = base + (qi >> 4);
        float4 z = make_float4(0.f, 0.f, 0.f, 0.f);
        sA[qi] = (row < n) ? agg4[(long)row * 16 + (qi & 15)] : z;
        sX[qi] = (row < n) ? x4[(long)row * 16 + (qi & 15)] : z;
    }
    __syncthreads();

    int w = t >> 6;
    float bias = b[c] + br[c];
    for (int r = w * 8; r < w * 8 + 8; ++r) {
        float a0 = 0.f, a1 = 0.f, r0 = 0.f, r1 = 0.f;
        #pragma unroll
        for (int q = 0; q < 16; q += 2) {
            float4 av0 = sA[r * 16 + q];
            float4 av1 = sA[r * 16 + q + 1];
            float4 xv0 = sX[r * 16 + q];
            float4 xv1 = sX[r * 16 + q + 1];
            a0 += av0.x * wA[q].x + av0.y * wA[q].y + av0.z * wA[q].z + av0.w * wA[q].w;
            a1 += av1.x * wA[q + 1].x + av1.y * wA[q + 1].y + av1.z * wA[q + 1].z + av1.w * wA[q + 1].w;
            r0 += xv0.x * wR[q].x + xv0.y * wR[q].y + xv0.z * wR[q].z + xv0.w * wR[q].w;
            r1 += xv1.x * wR[q + 1].x + xv1.y * wR[q + 1].y + xv1.z * wR[q + 1].z + xv1.w * wR[q + 1].w;
        }
        int grow = base + r;
        if (grow < n) out[(long)grow * 64 + c] = (a0 + a1) + (r0 + r1) + bias;
    }
}

extern "C" void kernel_launch(void* const* d_in, const int* in_sizes, int n_in,
                              void* d_out, int out_size, void* d_ws, size_t ws_size,
                              hipStream_t stream) {
    const float* x   = (const float*)d_in[0];
    const int*   src = (const int*)d_in[1];
    const int*   dst = (const int*)d_in[2];
    const float* W   = (const float*)d_in[3];
    const float* b   = (const float*)d_in[4];
    const float* Wr  = (const float*)d_in[5];
    const float* br  = (const float*)d_in[6];
    float* out = (float*)d_out;

    const int n = in_sizes[0] / 64;            // 50000
    const int e = in_sizes[1];                 // 800000
    const int nb = (e + TILE - 1) / TILE;      // 196 bucket blocks
    const int nrange = (n + 255) / 256;        // 196 node ranges
    const int m = 2 * 256 * nb;                // 100352 hist entries
    const int nbs = (m + 4095) / 4096;         // 25 scan blocks

    int*   H     = (int*)d_ws;                 // m   (16B-aligned: ws start)
    int*   Hoff  = H + m;                      // m
    int*   part  = Hoff + m;                   // 256
    int*   kdst  = part + 256;                 // e
    int*   ksrc  = kdst + e;                   // e
    int*   ksrc2 = ksrc + e;                   // e
    int*   roff  = ksrc2 + e;                  // n+1
    int*   col   = roff + n + 1;               // e
    float* ns    = (float*)(col + e);          // n
    float* xs    = ns + n;                     // n*64
    float* agg   = xs + (size_t)n * 64;        // n*64

    bucket_hist_kernel<<<nb, 256, 0, stream>>>(src, dst, H, e, nb);

    partial_kernel<<<nbs, 256, 0, stream>>>(H, part, m);
    scan_part_kernel<<<1, 256, 0, stream>>>(part, nbs);
    scan_final_kernel<<<nbs, 256, 0, stream>>>(H, part, Hoff, m);

    bucket_scatter_kernel<<<nb, 256, 0, stream>>>(src, dst, Hoff, kdst, ksrc, ksrc2, e, nb);

    csr_kernel<<<nrange, 256, 0, stream>>>(kdst, ksrc, Hoff, roff, col, n, e, nb, nrange);
    outdeg_kernel<<<nrange, 256, 0, stream>>>(ksrc2, Hoff, ns, n, e, nb, nrange);

    prescale_kernel<<<(n * 16 + 255) / 256, 256, 0, stream>>>(
        (const float4*)x, ns, (float4*)xs, n * 16);

    gather_kernel<<<(n * 64 + 255) / 256, 256, 0, stream>>>(
        (const float4*)xs, col, roff, (float4*)agg, n);

    out_kernel<<<(n + OR - 1) / OR, 256, 0, stream>>>(
        (const float4*)agg, (const float4*)x, W, b, Wr, br, out, n);
}